// Round 7
// baseline (375.149 us; speedup 1.0000x reference)
//
#include <hip/hip_runtime.h>
#include <hip/hip_bf16.h>
#include <hip/hip_cooperative_groups.h>

namespace cg = cooperative_groups;

// Problem constants: B=2048, D=3, K=64, H=768, N=4096
#define BATCH   2048
#define DEPTH   3
#define FANOUT  64
#define HID     768
#define NNODES  4096
#define NPAIRS  (BATCH * DEPTH)   // 6144
#define CAP     16
#define NTAIL   64                // fallback-path overflow blocks
#define SCHUNK  4
#define NCU     256

// ---- ws layout (ints) ----
#define WS_COUNT 0
#define WS_OCNT  4096
#define WS_NACT  4097
#define WS_QHEAD 4098
#define WS_ACT   4100                        // [4100, 8196): compacted active nodes
#define WS_LIST  (WS_ACT + NNODES)           // 8196
#define WS_OVFL  (WS_LIST + NNODES * CAP)    // 73732
#define WS_PART  (WS_OVFL + NPAIRS)          // 79876 (floats: per-pair CE loss)
#define WS_ZERO_INTS 4100

// R6-proven inner body: contiguous 3KB W row per wave-iteration, static SC,
// off-major interleaved 64-lane butterflies.
template <int SC>
__device__ __forceinline__ void compute_rows(
    const float4* __restrict__ w4,
    const float (*s_pool)[HID],
    float (*s_log)[FANOUT],
    const float* s_bias,
    int wave, int lane)
{
#pragma unroll 4
    for (int kk = 0; kk < 16; ++kk) {
        const int k = wave * 16 + kk;
        const float4* wr = w4 + (size_t)k * (HID / 4);
        float4 w0 = wr[lane], w1 = wr[lane + 64], w2 = wr[lane + 128];
        float v[SC];
#pragma unroll
        for (int s = 0; s < SC; ++s) {
            const float4* a4 = reinterpret_cast<const float4*>(&s_pool[s][0]);
            float4 a0 = a4[lane], a1 = a4[lane + 64], a2 = a4[lane + 128];
            v[s] = w0.x * a0.x + w0.y * a0.y + w0.z * a0.z + w0.w * a0.w
                 + w1.x * a1.x + w1.y * a1.y + w1.z * a1.z + w1.w * a1.w
                 + w2.x * a2.x + w2.y * a2.y + w2.z * a2.z + w2.w * a2.w;
        }
#pragma unroll
        for (int off = 32; off > 0; off >>= 1) {
#pragma unroll
            for (int s = 0; s < SC; ++s)
                v[s] += __shfl_xor(v[s], off, 64);
        }
        if (lane == 0) {
#pragma unroll
            for (int s = 0; s < SC; ++s)
                s_log[s][k] = v[s] + s_bias[k];
        }
    }
}

// Shared per-node body: process node n with sample list in s_pairs (c entries),
// write logits and per-pair CE partials.
template <bool WITH_PART>
__device__ __forceinline__ void process_node(
    const float* __restrict__ pooled,
    const float* __restrict__ W,
    const int*   __restrict__ path,
    float*       __restrict__ logits,
    float*       __restrict__ part,
    const int* s_pairs, int c, int n,
    const float* s_bias,
    float (*s_pool)[HID], float (*s_log)[FANOUT],
    int tid, int wave, int lane)
{
    const float4* w4 = reinterpret_cast<const float4*>(W + (size_t)n * FANOUT * HID);
    for (int base = 0; base < c; base += SCHUNK) {
        const int sc = min(c - base, SCHUNK);
        const int* pair_chunk = s_pairs + base;

        for (int idx = tid; idx < sc * (HID / 4); idx += 256) {
            int s = idx / (HID / 4), f = idx % (HID / 4);
            int b = pair_chunk[s] / DEPTH;
            reinterpret_cast<float4*>(&s_pool[s][0])[f] =
                reinterpret_cast<const float4*>(pooled + (size_t)b * HID)[f];
        }
        __syncthreads();

        switch (sc) {
        case 1: compute_rows<1>(w4, s_pool, s_log, s_bias, wave, lane); break;
        case 2: compute_rows<2>(w4, s_pool, s_log, s_bias, wave, lane); break;
        case 3: compute_rows<3>(w4, s_pool, s_log, s_bias, wave, lane); break;
        default: compute_rows<4>(w4, s_pool, s_log, s_bias, wave, lane); break;
        }
        __syncthreads();

        for (int idx = tid; idx < sc * FANOUT; idx += 256) {
            int s = idx >> 6, k = idx & 63;
            logits[(size_t)pair_chunk[s] * FANOUT + k] = s_log[s][k];
        }
        if (WITH_PART) {
            for (int s = wave; s < sc; s += 4) {
                int pair = pair_chunk[s];
                float x = s_log[s][lane];
                float m = x;
#pragma unroll
                for (int off = 32; off > 0; off >>= 1)
                    m = fmaxf(m, __shfl_xor(m, off, 64));
                float e = expf(x - m);
#pragma unroll
                for (int off = 32; off > 0; off >>= 1)
                    e += __shfl_xor(e, off, 64);
                if (lane == 0) {
                    int t = path[pair];
                    part[pair] = m + logf(e) - s_log[s][t];
                }
            }
        }
        __syncthreads();
    }
}

// ================= Cooperative fused kernel =================
__global__ __launch_bounds__(256) void fused_kernel(
    const float* __restrict__ pooled,
    const float* __restrict__ W,
    const float* __restrict__ bias,
    const int*   __restrict__ nodes,
    const int*   __restrict__ path,
    int*         __restrict__ ws,
    float*       __restrict__ losses,
    float*       __restrict__ logits)
{
    cg::grid_group grid = cg::this_grid();
    const int tid  = threadIdx.x;
    const int wave = tid >> 6;
    const int lane = tid & 63;
    const int gstride = gridDim.x * 256;
    float* part = reinterpret_cast<float*>(ws) + WS_PART;

    // ---- Phase 1: bin pairs, build compacted active-node list ----
    for (int idx = blockIdx.x * 256 + tid; idx < NPAIRS; idx += gstride) {
        int n = nodes[idx];
        int pos = atomicAdd(&ws[WS_COUNT + n], 1);
        if (pos == 0) {
            int a = atomicAdd(&ws[WS_NACT], 1);
            ws[WS_ACT + a] = n;
        }
        if (pos < CAP) {
            ws[WS_LIST + n * CAP + pos] = idx;
        } else {
            int op = atomicAdd(&ws[WS_OCNT], 1);
            ws[WS_OVFL + op] = idx;
        }
    }
    __threadfence();
    grid.sync();

    // ---- Phase 2: dynamic queue over active nodes (+ overflow items) ----
    __shared__ int   s_i;
    __shared__ int   s_pairs[CAP];
    __shared__ float s_bias[FANOUT];
    __shared__ float s_pool[SCHUNK][HID];
    __shared__ float s_log[SCHUNK][FANOUT];

    const int nact = ws[WS_NACT];
    const int oc   = min(ws[WS_OCNT], NPAIRS);
    const int ntot = nact + oc;

    for (;;) {
        if (tid == 0) s_i = atomicAdd(&ws[WS_QHEAD], 1);
        __syncthreads();
        const int i = s_i;
        if (i >= ntot) break;

        int n, c;
        if (i < nact) {
            n = ws[WS_ACT + i];
            c = min(ws[WS_COUNT + n], CAP);
            if (tid < c) s_pairs[tid] = ws[WS_LIST + n * CAP + tid];
        } else {
            int pair = ws[WS_OVFL + (i - nact)];
            n = nodes[pair];
            c = 1;
            if (tid == 0) s_pairs[0] = pair;
        }
        if (tid < FANOUT) s_bias[tid] = bias[(size_t)n * FANOUT + tid];
        __syncthreads();

        process_node<true>(pooled, W, path, logits, part,
                           s_pairs, c, n, s_bias, s_pool, s_log, tid, wave, lane);
        // process_node ends with __syncthreads -> safe to rewrite s_i
    }

    __threadfence();
    grid.sync();

    // ---- Phase 3: per-sample loss sum (fixed order d=0,1,2) ----
    for (int b = blockIdx.x * 256 + tid; b < BATCH; b += gstride)
        losses[b] = part[b * 3 + 0] + part[b * 3 + 1] + part[b * 3 + 2];
}

// ================= Fallback path (R6-proven, non-cooperative) =================
__global__ __launch_bounds__(256) void bin_kernel(const int* __restrict__ nodes,
                                                  int* __restrict__ ws) {
    int idx = blockIdx.x * 256 + threadIdx.x;
    if (idx >= NPAIRS) return;
    int n = nodes[idx];
    int pos = atomicAdd(&ws[WS_COUNT + n], 1);
    if (pos < CAP) {
        ws[WS_LIST + n * CAP + pos] = idx;
    } else {
        int op = atomicAdd(&ws[WS_OCNT], 1);
        ws[WS_OVFL + op] = idx;
    }
}

__global__ __launch_bounds__(256) void node_gemm_kernel(
    const float* __restrict__ pooled,
    const float* __restrict__ W,
    const float* __restrict__ bias,
    const int*   __restrict__ nodes,
    int*         __restrict__ ws,
    float*       __restrict__ logits)
{
    __shared__ int   s_pairs[CAP];
    __shared__ float s_bias[FANOUT];
    __shared__ float s_pool[SCHUNK][HID];
    __shared__ float s_log[SCHUNK][FANOUT];

    const int tid  = threadIdx.x;
    const int wave = tid >> 6;
    const int lane = tid & 63;

    int c = 0, n = -1;
    if (blockIdx.x < NNODES) {
        n = blockIdx.x;
        c = ws[WS_COUNT + n];
        if (c == 0) return;
        c = min(c, CAP);
        if (tid < c) s_pairs[tid] = ws[WS_LIST + (size_t)n * CAP + tid];
    } else {
        const int ocnt = min(ws[WS_OCNT], NPAIRS);
        const int i  = (int)blockIdx.x - NNODES;
        if (i >= ocnt) return;
        c = 1;
        if (tid == 0) s_pairs[0] = ws[WS_OVFL + i];
        __syncthreads();
        n = nodes[s_pairs[0]];
    }
    if (tid < FANOUT) s_bias[tid] = bias[(size_t)n * FANOUT + tid];
    __syncthreads();

    process_node<false>(pooled, W, nullptr, logits, nullptr,
                        s_pairs, c, n, s_bias, s_pool, s_log, tid, wave, lane);
}

__global__ __launch_bounds__(256) void loss_kernel(
    const float* __restrict__ logits,
    const int*   __restrict__ path,
    float*       __restrict__ losses)
{
    const int wave = threadIdx.x >> 6;
    const int lane = threadIdx.x & 63;
    const int b = blockIdx.x * 4 + wave;
    if (b >= BATCH) return;
    const float* lg = logits + (size_t)b * DEPTH * FANOUT;
    float loss = 0.f;
#pragma unroll
    for (int d = 0; d < DEPTH; ++d) {
        float x = lg[d * FANOUT + lane];
        float m = x;
#pragma unroll
        for (int off = 32; off > 0; off >>= 1)
            m = fmaxf(m, __shfl_xor(m, off, 64));
        float e = expf(x - m);
#pragma unroll
        for (int off = 32; off > 0; off >>= 1)
            e += __shfl_xor(e, off, 64);
        float lse = m + logf(e);
        int t = path[b * DEPTH + d];
        loss += lse - __shfl(x, t, 64);
    }
    if (lane == 0) losses[b] = loss;
}

extern "C" void kernel_launch(void* const* d_in, const int* in_sizes, int n_in,
                              void* d_out, int out_size, void* d_ws, size_t ws_size,
                              hipStream_t stream) {
    const float* pooled = (const float*)d_in[0];  // [B, H]
    const int*   nodes  = (const int*)d_in[1];    // [B, D]
    const int*   path   = (const int*)d_in[2];    // [B, D]
    const float* W      = (const float*)d_in[3];  // [N, K, H]
    const float* bias   = (const float*)d_in[4];  // [N, K]

    float* losses = (float*)d_out;                // [B]
    float* logits = (float*)d_out + BATCH;        // [B, D, K]
    int*   ws     = (int*)d_ws;

    hipMemsetAsync(ws, 0, WS_ZERO_INTS * sizeof(int), stream);

    // Size the cooperative grid from queried occupancy (deterministic).
    int nb = 0;
    hipError_t qerr = hipOccupancyMaxActiveBlocksPerMultiprocessor(
        &nb, (const void*)fused_kernel, 256, 0);
    if (qerr != hipSuccess || nb < 1) nb = 1;
    if (nb > 8) nb = 8;
    dim3 grid(nb * NCU), block(256);

    void* args[] = {(void*)&pooled, (void*)&W, (void*)&bias, (void*)&nodes,
                    (void*)&path, (void*)&ws, (void*)&losses, (void*)&logits};
    hipError_t lerr = hipLaunchCooperativeKernel(
        (const void*)fused_kernel, grid, block, args, 0, stream);

    if (lerr != hipSuccess) {
        // Fallback: proven 4-dispatch path (same compute body)
        hipLaunchKernelGGL(bin_kernel, dim3((NPAIRS + 255) / 256), dim3(256),
                           0, stream, nodes, ws);
        hipLaunchKernelGGL(node_gemm_kernel, dim3(NNODES + NTAIL), dim3(256),
                           0, stream, pooled, W, bias, nodes, ws, logits);
        hipLaunchKernelGGL(loss_kernel, dim3((BATCH + 3) / 4), dim3(256),
                           0, stream, logits, path, losses);
    }
}

// Round 8
// 136.684 us; speedup vs baseline: 2.7446x; 2.7446x over previous
//
#include <hip/hip_runtime.h>
#include <hip/hip_bf16.h>

// Problem constants: B=2048, D=3, K=64, H=768, N=4096
#define BATCH   2048
#define DEPTH   3
#define FANOUT  64
#define HID     768
#define NNODES  4096
#define NPAIRS  (BATCH * DEPTH)   // 6144
#define CAP     16                // per-node capacity before overflow
#define NTAIL   64                // overflow tail blocks (dormant in practice)
#define SCHUNK  4                 // samples per W pass

// ---- ws layout (ints) ----
#define WS_COUNT 0
#define WS_OCNT  NNODES                     // 4096 (1 int, padded to 4)
#define WS_LIST  (NNODES + 4)               // 4100
#define WS_OVFL  (WS_LIST + NNODES * CAP)   // 69636
#define WS_PART  (WS_OVFL + NPAIRS)         // 75780 (floats: per-pair CE loss)
#define WS_ZERO_INTS (NNODES + 4)

__global__ __launch_bounds__(256) void bin_kernel(const int* __restrict__ nodes,
                                                  int* __restrict__ ws) {
    int idx = blockIdx.x * 256 + threadIdx.x;
    if (idx >= NPAIRS) return;
    int n = nodes[idx];
    int pos = atomicAdd(&ws[WS_COUNT + n], 1);
    if (pos < CAP) {
        ws[WS_LIST + n * CAP + pos] = idx;
    } else {
        int op = atomicAdd(&ws[WS_OCNT], 1);
        ws[WS_OVFL + op] = idx;
    }
}

// R6-proven inner body: contiguous 3KB W row per wave-iteration, static SC,
// off-major interleaved 64-lane butterflies.
template <int SC>
__device__ __forceinline__ void compute_rows(
    const float4* __restrict__ w4,
    const float (*s_pool)[HID],
    float (*s_log)[FANOUT],
    const float* s_bias,
    int wave, int lane)
{
#pragma unroll 4
    for (int kk = 0; kk < 16; ++kk) {
        const int k = wave * 16 + kk;
        const float4* wr = w4 + (size_t)k * (HID / 4);
        float4 w0 = wr[lane], w1 = wr[lane + 64], w2 = wr[lane + 128];
        float v[SC];
#pragma unroll
        for (int s = 0; s < SC; ++s) {
            const float4* a4 = reinterpret_cast<const float4*>(&s_pool[s][0]);
            float4 a0 = a4[lane], a1 = a4[lane + 64], a2 = a4[lane + 128];
            v[s] = w0.x * a0.x + w0.y * a0.y + w0.z * a0.z + w0.w * a0.w
                 + w1.x * a1.x + w1.y * a1.y + w1.z * a1.z + w1.w * a1.w
                 + w2.x * a2.x + w2.y * a2.y + w2.z * a2.z + w2.w * a2.w;
        }
#pragma unroll
        for (int off = 32; off > 0; off >>= 1) {
#pragma unroll
            for (int s = 0; s < SC; ++s)
                v[s] += __shfl_xor(v[s], off, 64);
        }
        if (lane == 0) {
#pragma unroll
            for (int s = 0; s < SC; ++s)
                s_log[s][k] = v[s] + s_bias[k];
        }
    }
}

// One block per node (XCD-swizzled); tail blocks sweep the overflow list.
// CE partials fused (R4-proven), summed by loss_sum_kernel.
__global__ __launch_bounds__(256) void node_gemm_kernel(
    const float* __restrict__ pooled,   // [B, H]
    const float* __restrict__ W,        // [N, K, H]
    const float* __restrict__ bias,     // [N, K]
    const int*   __restrict__ nodes,    // [B, D]
    const int*   __restrict__ path,     // [B, D]
    int*         __restrict__ ws,
    float*       __restrict__ logits)   // [B, D, K]
{
    __shared__ int   s_pairs[CAP];
    __shared__ float s_bias[FANOUT];
    __shared__ float s_pool[SCHUNK][HID];
    __shared__ float s_log[SCHUNK][FANOUT];

    const int tid  = threadIdx.x;
    const int wave = tid >> 6;
    const int lane = tid & 63;
    float* part = reinterpret_cast<float*>(ws) + WS_PART;

    int c = 0;
    int n = -1;

    if (blockIdx.x < NNODES) {
        // Bijective XCD swizzle (4096 % 8 == 0): XCD x streams the contiguous
        // 96MB W partition of nodes [x*512, (x+1)*512).
        const int orig = blockIdx.x;
        n = (orig & 7) * (NNODES / 8) + (orig >> 3);
        c = ws[WS_COUNT + n];
        if (c == 0) return;
        c = min(c, CAP);
        if (tid < c) s_pairs[tid] = ws[WS_LIST + (size_t)n * CAP + tid];
    } else {
        const int oc = min(ws[WS_OCNT], NPAIRS);
        const int i  = (int)blockIdx.x - NNODES;
        if (i >= oc) return;
        c = 1;
        if (tid == 0) s_pairs[0] = ws[WS_OVFL + i];
        __syncthreads();
        n = nodes[s_pairs[0]];
    }
    if (tid < FANOUT) s_bias[tid] = bias[(size_t)n * FANOUT + tid];
    __syncthreads();

    const float4* w4 = reinterpret_cast<const float4*>(W + (size_t)n * FANOUT * HID);

    for (int base = 0; base < c; base += SCHUNK) {
        const int sc = min(c - base, SCHUNK);
        const int* pair_chunk = s_pairs + base;

        // Stage the sc pooled vectors into LDS (coalesced float4)
        for (int idx = tid; idx < sc * (HID / 4); idx += 256) {
            int s = idx / (HID / 4);
            int f = idx % (HID / 4);
            int b = pair_chunk[s] / DEPTH;
            reinterpret_cast<float4*>(&s_pool[s][0])[f] =
                reinterpret_cast<const float4*>(pooled + (size_t)b * HID)[f];
        }
        __syncthreads();

        switch (sc) {
        case 1: compute_rows<1>(w4, s_pool, s_log, s_bias, wave, lane); break;
        case 2: compute_rows<2>(w4, s_pool, s_log, s_bias, wave, lane); break;
        case 3: compute_rows<3>(w4, s_pool, s_log, s_bias, wave, lane); break;
        default: compute_rows<4>(w4, s_pool, s_log, s_bias, wave, lane); break;
        }
        __syncthreads();

        // Coalesced logits writeout
        for (int idx = tid; idx < sc * FANOUT; idx += 256) {
            int s = idx >> 6, k = idx & 63;
            logits[(size_t)pair_chunk[s] * FANOUT + k] = s_log[s][k];
        }

        // Per-pair CE partial loss (wave-parallel over samples, lane = k)
        for (int s = wave; s < sc; s += 4) {
            int pair = pair_chunk[s];
            float x = s_log[s][lane];
            float m = x;
#pragma unroll
            for (int off = 32; off > 0; off >>= 1)
                m = fmaxf(m, __shfl_xor(m, off, 64));
            float e = expf(x - m);
#pragma unroll
            for (int off = 32; off > 0; off >>= 1)
                e += __shfl_xor(e, off, 64);
            if (lane == 0) {
                int t = path[pair];
                part[pair] = m + logf(e) - s_log[s][t];
            }
        }
        __syncthreads();   // protect s_pool/s_log before next chunk
    }
}

// Deterministic per-sample loss sum (fixed order d=0,1,2)
__global__ __launch_bounds__(256) void loss_sum_kernel(const int* __restrict__ ws,
                                                       float* __restrict__ losses) {
    const float* part = reinterpret_cast<const float*>(ws) + WS_PART;
    int b = blockIdx.x * 256 + threadIdx.x;
    if (b < BATCH)
        losses[b] = part[b * 3 + 0] + part[b * 3 + 1] + part[b * 3 + 2];
}

extern "C" void kernel_launch(void* const* d_in, const int* in_sizes, int n_in,
                              void* d_out, int out_size, void* d_ws, size_t ws_size,
                              hipStream_t stream) {
    const float* pooled = (const float*)d_in[0];  // [B, H]
    const int*   nodes  = (const int*)d_in[1];    // [B, D]
    const int*   path   = (const int*)d_in[2];    // [B, D]
    const float* W      = (const float*)d_in[3];  // [N, K, H]
    const float* bias   = (const float*)d_in[4];  // [N, K]

    float* losses = (float*)d_out;                // [B]
    float* logits = (float*)d_out + BATCH;        // [B, D, K]
    int*   ws     = (int*)d_ws;

    hipMemsetAsync(ws, 0, WS_ZERO_INTS * sizeof(int), stream);
    hipLaunchKernelGGL(bin_kernel, dim3((NPAIRS + 255) / 256), dim3(256),
                       0, stream, nodes, ws);
    hipLaunchKernelGGL(node_gemm_kernel, dim3(NNODES + NTAIL), dim3(256),
                       0, stream, pooled, W, bias, nodes, path, ws, logits);
    hipLaunchKernelGGL(loss_sum_kernel, dim3((BATCH + 255) / 256), dim3(256),
                       0, stream, ws, losses);
}